// Round 11
// baseline (494.962 us; speedup 1.0000x reference)
//
#include <hip/hip_runtime.h>
#include <math.h>

constexpr int BATCH = 4;
constexpr int SEQ   = 2048;
constexpr int HID   = 2048;
constexpr int NHEAD = 8;
constexpr int HD    = 256;
constexpr int QKVN  = (NHEAD + 2) * HD;          // 2560
constexpr float SCL = 0.0625f;                   // 256^-0.5

typedef __bf16 bf16_t;
typedef __bf16 bf16x8 __attribute__((ext_vector_type(8)));
typedef float  f32x4  __attribute__((ext_vector_type(4)));

__device__ __forceinline__ f32x4 zero4() {
  f32x4 z; z[0] = 0.f; z[1] = 0.f; z[2] = 0.f; z[3] = 0.f; return z;
}

__device__ __forceinline__ f32x4 mfma16(bf16x8 a, bf16x8 b, f32x4 c) {
  return __builtin_amdgcn_mfma_f32_16x16x32_bf16(a, b, c, 0, 0, 0);
}

// async global->LDS, 16B per lane. lds must be wave-uniform base; HW adds lane*16.
__device__ __forceinline__ void gl2lds16(const void* g, void* lds) {
  typedef __attribute__((address_space(1))) void* gp_t;
  typedef __attribute__((address_space(3))) void* lp_t;
  __builtin_amdgcn_global_load_lds((gp_t)(size_t)g,
                                   (lp_t)(unsigned int)(size_t)lds, 16, 0, 0);
}

__device__ __forceinline__ float rmax16(float v) {
#pragma unroll
  for (int o = 1; o < 16; o <<= 1) v = fmaxf(v, __shfl_xor(v, o));
  return v;
}
__device__ __forceinline__ float rsum16(float v) {
#pragma unroll
  for (int o = 1; o < 16; o <<= 1) v += __shfl_xor(v, o);
  return v;
}

// ---------- fp32 -> bf16 bulk convert (8 elems/thread) ----------
__global__ __launch_bounds__(256)
void cvt_bf16_kernel(const float* __restrict__ in, bf16_t* __restrict__ out) {
  const int i = blockIdx.x * 256 + threadIdx.x;
  const float4 a = ((const float4*)in)[i * 2];
  const float4 b = ((const float4*)in)[i * 2 + 1];
  bf16x8 o;
  o[0] = (bf16_t)a.x; o[1] = (bf16_t)a.y; o[2] = (bf16_t)a.z; o[3] = (bf16_t)a.w;
  o[4] = (bf16_t)b.x; o[5] = (bf16_t)b.y; o[6] = (bf16_t)b.z; o[7] = (bf16_t)b.w;
  ((bf16x8*)out)[i] = o;
}

// ---------- w[K][N] fp32 -> wT[N][K] bf16, 64x64 tiles ----------
__global__ __launch_bounds__(256)
void transw_kernel(const float* __restrict__ w, bf16_t* __restrict__ wT, int K, int N) {
  __shared__ __align__(16) bf16_t tile[64][72];
  const int n0 = blockIdx.x * 64, k0 = blockIdx.y * 64;
  const int t = threadIdx.x, rr = t >> 3, c8 = (t & 7) * 8;
#pragma unroll
  for (int it = 0; it < 2; ++it) {
    const int r = rr + it * 32;
    const float4* p = (const float4*)(w + (size_t)(k0 + r) * N + n0 + c8);
    const float4 a = p[0], b = p[1];
    bf16x8 o;
    o[0] = (bf16_t)a.x; o[1] = (bf16_t)a.y; o[2] = (bf16_t)a.z; o[3] = (bf16_t)a.w;
    o[4] = (bf16_t)b.x; o[5] = (bf16_t)b.y; o[6] = (bf16_t)b.z; o[7] = (bf16_t)b.w;
    *(bf16x8*)&tile[r][c8] = o;
  }
  __syncthreads();
#pragma unroll
  for (int it = 0; it < 2; ++it) {
    const int rn = rr + it * 32;
    bf16x8 o;
#pragma unroll
    for (int j = 0; j < 8; ++j) o[j] = tile[c8 + j][rn];
    *(bf16x8*)&wT[(size_t)(n0 + rn) * K + k0 + c8] = o;
  }
}

// =====================================================================
// 256x256 GEMM, 4-phase merged schedule (from the 8-phase m201 port):
// same dataflow/lead/hazard structure, HALF the barriers (8/iter vs 16)
// and 32-MFMA clusters (vs 16) -- theory: barrier resync + counted-wait
// retirement 16x/iter was the ~19K cyc/iter stall at 2 waves/SIMD.
// + T1 bijective XCD swizzle (grids 320 and 256, both % 8 == 0).
// vmcnt ledger (steady state): enter Q1 with t1.A in flight(4);
// Q1 +t1.B(4); Q2 +t2.A(4), VMC(4) drains t1.A+t1.B before Q3 reads t1;
// Q3 +t2.B(4); Q4 +t3.A(4), VMC(4) drains t2 before next Q1.
// Last iter: Q2 must VMC(0) (only t1.B outstanding; vmcnt(4) wouldn't wait).
// =====================================================================
#define BAR()   __builtin_amdgcn_s_barrier()
#define LGKM0() do { asm volatile("s_waitcnt lgkmcnt(0)" ::: "memory"); \
                     __builtin_amdgcn_sched_barrier(0); } while (0)
#define VMC(n)  asm volatile("s_waitcnt vmcnt(" #n ")" ::: "memory")

template <typename TC>
__global__ __launch_bounds__(512)
void gemm256_kernel(const bf16_t* __restrict__ A, const bf16_t* __restrict__ BT,
                    TC* __restrict__ C, int M, int N, int K) {
  __shared__ __align__(16) bf16_t As[2][2][128 * 64];   // [buf][half] 64 KB
  __shared__ __align__(16) bf16_t Bs[2][2][128 * 64];   // 64 KB

  const int tid = threadIdx.x;
  const int w = tid >> 6, lane = tid & 63;
  const int wr = w >> 2, wc = w & 3;
  const int quad = lane >> 4, l15 = lane & 15;

  // T1: XCD-aware bijective remap (nwg % 8 == 0 for both launches)
  const int gx = gridDim.x;
  const int nwg = gx * gridDim.y;
  const int flat = blockIdx.y * gx + blockIdx.x;
  const int cpx = nwg >> 3;
  const int swz = (flat & 7) * cpx + (flat >> 3);
  const int bm = (swz / gx) * 256, bn = (swz % gx) * 256;

  const int srow = tid >> 3;                    // 0..63 row within 64-row chunk
  const int sc16 = (tid & 7) ^ (srow & 7);      // pre-swizzled source chunk
  const bf16_t* Asrc = A  + (size_t)(bm + srow) * K + sc16 * 8;
  const bf16_t* Bsrc = BT + (size_t)(bn + srow) * K + sc16 * 8;

#define STAGE_A(t, h) do {                                                  \
    const bf16_t* _s = Asrc + (size_t)((h) * 128) * K + (t) * 64;           \
    gl2lds16(_s,                 &As[(t) & 1][h][w * 512]);                 \
    gl2lds16(_s + (size_t)64 * K, &As[(t) & 1][h][4096 + w * 512]);         \
  } while (0)
#define STAGE_B(t, h) do {                                                  \
    const bf16_t* _s = Bsrc + (size_t)((h) * 128) * K + (t) * 64;           \
    gl2lds16(_s,                 &Bs[(t) & 1][h][w * 512]);                 \
    gl2lds16(_s + (size_t)64 * K, &Bs[(t) & 1][h][4096 + w * 512]);         \
  } while (0)

  const int c0  = ((quad ^ (l15 & 7)) << 3);
  const int aro = l15 * 64;                     // + mt*1024
  const int bh  = wc >> 1;
  const int bro = ((wc & 1) * 64 + l15) * 64;   // + nt*1024

  f32x4 acc[8][4];
#pragma unroll
  for (int mt = 0; mt < 8; ++mt)
#pragma unroll
    for (int nt = 0; nt < 4; ++nt) acc[mt][nt] = zero4();

  bf16x8 bfr[4][2], a01[2][2], a2[6][2];

#define LD_B(b) do { _Pragma("unroll")                                      \
    for (int nt = 0; nt < 4; ++nt) {                                        \
      bfr[nt][0] = *(const bf16x8*)&Bs[b][bh][bro + nt * 1024 + c0];        \
      bfr[nt][1] = *(const bf16x8*)&Bs[b][bh][bro + nt * 1024 + (c0 ^ 32)]; \
    } } while (0)
#define LD_A01(b) do { _Pragma("unroll")                                    \
    for (int mt = 0; mt < 2; ++mt) {                                        \
      a01[mt][0] = *(const bf16x8*)&As[b][wr][aro + mt * 1024 + c0];        \
      a01[mt][1] = *(const bf16x8*)&As[b][wr][aro + mt * 1024 + (c0 ^ 32)]; \
    } } while (0)
#define LD_A2(b) do { _Pragma("unroll")                                     \
    for (int i = 0; i < 6; ++i) {                                           \
      a2[i][0] = *(const bf16x8*)&As[b][wr][aro + (i + 2) * 1024 + c0];     \
      a2[i][1] = *(const bf16x8*)&As[b][wr][aro + (i + 2) * 1024 + (c0^32)];\
    } } while (0)
#define MFMA8(A0, A1, mb) do {                                              \
    __builtin_amdgcn_s_setprio(1);                                          \
    _Pragma("unroll")                                                       \
    for (int nt = 0; nt < 4; ++nt) {                                        \
      acc[(mb)][nt]     = mfma16((A0)[0], bfr[nt][0], acc[(mb)][nt]);       \
      acc[(mb)][nt]     = mfma16((A0)[1], bfr[nt][1], acc[(mb)][nt]);       \
      acc[(mb)+1][nt]   = mfma16((A1)[0], bfr[nt][0], acc[(mb)+1][nt]);     \
      acc[(mb)+1][nt]   = mfma16((A1)[1], bfr[nt][1], acc[(mb)+1][nt]);     \
    }                                                                       \
    __builtin_amdgcn_s_setprio(0);                                          \
  } while (0)

  const int NITER = K >> 7;                     // K/128 (two BK=64 tiles/iter)

  // prologue: t0 fully + t1.A; drain t0, keep t1.A in flight
  STAGE_A(0, 0); STAGE_A(0, 1); STAGE_B(0, 0); STAGE_B(0, 1);
  STAGE_A(1, 0); STAGE_A(1, 1);
  VMC(4);
  BAR();

  for (int u = 0; u < NITER; ++u) {
    const bool last = (u == NITER - 1);
    const int t1 = 2 * u + 1, t2 = 2 * u + 2, t3 = 2 * u + 3;

    // ===== Q1: all reads of buf0 (24 ds_reads); stage t1.B =====
    LD_B(0); LD_A01(0); LD_A2(0);
    STAGE_B(t1, 0); STAGE_B(t1, 1);
    BAR(); LGKM0();
    MFMA8(a01[0], a01[1], 0);
    MFMA8(a2[0], a2[1], 2);
    BAR();
    // ===== Q2: stage t2.A; drain so t1 fully resident before Q3 =====
    if (!last) { STAGE_A(t2, 0); STAGE_A(t2, 1); VMC(4); } else { VMC(0); }
    BAR();
    MFMA8(a2[2], a2[3], 4);
    MFMA8(a2[4], a2[5], 6);
    BAR();
    // ===== Q3: all reads of buf1 (24 ds_reads); stage t2.B =====
    LD_B(1); LD_A01(1); LD_A2(1);
    if (!last) { STAGE_B(t2, 0); STAGE_B(t2, 1); }
    BAR(); LGKM0();
    MFMA8(a01[0], a01[1], 0);
    MFMA8(a2[0], a2[1], 2);
    BAR();
    // ===== Q4: stage t3.A; drain so t2 fully resident before next Q1 =====
    if (!last) { STAGE_A(t3, 0); STAGE_A(t3, 1); VMC(4); }
    BAR();
    MFMA8(a2[2], a2[3], 4);
    MFMA8(a2[4], a2[5], 6);
    BAR();
  }

#pragma unroll
  for (int mt = 0; mt < 8; ++mt)
#pragma unroll
    for (int nt = 0; nt < 4; ++nt)
#pragma unroll
      for (int r = 0; r < 4; ++r) {
        const int row = bm + wr * 128 + mt * 16 + quad * 4 + r;
        const int col = bn + wc * 64 + nt * 16 + l15;
        C[(size_t)row * N + col] = (TC)acc[mt][nt][r];
      }
#undef STAGE_A
#undef STAGE_B
#undef LD_B
#undef LD_A01
#undef LD_A2
#undef MFMA8
}

// ---------- RoPE cos/sin table: tab[s][i] = (cos, sin) ----------
__global__ __launch_bounds__(128)
void rope_table_kernel(const int* __restrict__ pos, float2* __restrict__ tab) {
  const int s = blockIdx.x, i = threadIdx.x;
  const float inv_freq = powf(10000.0f, -(float)i / 128.0f);
  const float ang = (float)pos[s] * inv_freq;
  float sn, cs;
  sincosf(ang, &sn, &cs);
  tab[s * 128 + i] = make_float2(cs, sn);
}

// ---------- RoPE apply, table-driven, bf16x8 vectorized ----------
__global__ __launch_bounds__(256)
void rope_kernel(const float2* __restrict__ tab, bf16_t* __restrict__ qkv) {
  const int bs = blockIdx.x * 16 + (threadIdx.x >> 4);
  const int h  = blockIdx.y;
  const int i0 = (threadIdx.x & 15) * 8;
  const int s  = bs & (SEQ - 1);
  const size_t base = (size_t)bs * QKVN + (size_t)h * HD;
  bf16x8 a = *(const bf16x8*)&qkv[base + i0];
  bf16x8 b = *(const bf16x8*)&qkv[base + 128 + i0];
  bf16x8 oa, ob;
#pragma unroll
  for (int j = 0; j < 8; ++j) {
    const float2 t = tab[s * 128 + i0 + j];
    const float x1 = (float)a[j], x2 = (float)b[j];
    oa[j] = (bf16_t)(x1 * t.x - x2 * t.y);
    ob[j] = (bf16_t)(x2 * t.x + x1 * t.y);
  }
  *(bf16x8*)&qkv[base + i0]       = oa;
  *(bf16x8*)&qkv[base + 128 + i0] = ob;
}

// ---------- V transpose: qkv v-part [s][d] -> Vt[b][d][s] ----------
__global__ __launch_bounds__(256)
void vtrans_kernel(const bf16_t* __restrict__ qkv, bf16_t* __restrict__ Vt) {
  __shared__ __align__(16) bf16_t tile[64][72];
  const int s0 = blockIdx.x * 64, d0 = blockIdx.y * 64, b = blockIdx.z;
  const int t = threadIdx.x, rr = t >> 3, c8 = (t & 7) * 8;
#pragma unroll
  for (int it = 0; it < 2; ++it) {
    const int r = rr + it * 32;
    *(bf16x8*)&tile[r][c8] =
        *(const bf16x8*)&qkv[(size_t)(b * SEQ + s0 + r) * QKVN + 2304 + d0 + c8];
  }
  __syncthreads();
#pragma unroll
  for (int it = 0; it < 2; ++it) {
    const int dd = rr + it * 32;
    bf16x8 o;
#pragma unroll
    for (int j = 0; j < 8; ++j) o[j] = tile[c8 + j][dd];
    *(bf16x8*)&Vt[(size_t)(b * HD + d0 + dd) * SEQ + s0 + c8] = o;
  }
}

// ---------- flash attention (round-1 config: PROVEN LOCAL OPTIMUM, 137.6 us)
// 8 waves = 8 heads share K/V tiles; fused complementary q-pair (qt, 127-qt)
// per block -> uniform ~33 K-tile iterations; 2-phase prefetch (stage kt+1
// into buf^1 while computing kt). 9 structural variants all regressed.
__global__ __launch_bounds__(512)
void attn_kernel(const bf16_t* __restrict__ qkv, const bf16_t* __restrict__ Vt,
                 bf16_t* __restrict__ O) {
  __shared__ __align__(16) bf16_t Ks[2][64 * 256];
  __shared__ __align__(16) bf16_t Vts[2][256 * 64];
  __shared__ __align__(16) bf16_t Pl[8][16][72];

  const int tid = threadIdx.x, w = tid >> 6, lane = tid & 63;
  const int quad = lane >> 4, l15 = lane & 15;
  const int b = blockIdx.x >> 6;
  const int qtR = blockIdx.x & 63;
  const int h = w;

  const int krow_base = w * 2 + (lane >> 5);
  const int kcol = lane & 31;
  const int vrow_base = w * 8 + (lane >> 3);
  const int vcol = lane & 7;

  const bf16_t* kbase0 = qkv + (size_t)(b * SEQ) * QKVN + 2048;
  const bf16_t* vbase0 = Vt + (size_t)b * HD * SEQ;

  auto stage = [&](int kt, int buf) {
    const bf16_t* kbase = kbase0 + (size_t)(kt * 64) * QKVN;
#pragma unroll
    for (int i = 0; i < 4; ++i) {
      const int r = i * 16 + krow_base;
      gl2lds16(kbase + (size_t)r * QKVN + ((kcol ^ (r & 31)) << 3),
               &Ks[buf][(i * 512 + w * 64) * 8]);
    }
    const bf16_t* vbase = vbase0 + kt * 64;
#pragma unroll
    for (int i = 0; i < 4; ++i) {
      const int r = i * 64 + vrow_base;
      gl2lds16(vbase + (size_t)r * SEQ + ((vcol ^ (r & 7)) << 3),
               &Vts[buf][(i * 512 + w * 64) * 8]);
    }
  };

  for (int phase = 0; phase < 2; ++phase) {
    const int qt = phase ? (127 - qtR) : qtR;
    const int q0 = qt * 16;

    bf16x8 qf[8];
    const bf16_t* qp =
        qkv + (size_t)(b * SEQ + q0 + l15) * QKVN + (size_t)h * HD + quad * 8;
#pragma unroll
    for (int ks = 0; ks < 8; ++ks) qf[ks] = *(const bf16x8*)(qp + ks * 32);

    float mrun[4], lrun[4];
    f32x4 of[16];
#pragma unroll
    for (int r = 0; r < 4; ++r) { mrun[r] = -3e38f; lrun[r] = 0.f; }
#pragma unroll
    for (int dt = 0; dt < 16; ++dt) of[dt] = zero4();

    const int ntiles = q0 / 64 + 1;
    int cur = 0;
    stage(0, 0);
    __syncthreads();

    for (int kt = 0; kt < ntiles; ++kt) {
      if (kt + 1 < ntiles) stage(kt + 1, cur ^ 1);

      const bf16_t* ksb = Ks[cur];
      const bf16_t* vsb = Vts[cur];

      f32x4 sf[4];
#pragma unroll
      for (int nt = 0; nt < 4; ++nt) {
        f32x4 acc = zero4();
        const int row = nt * 16 + l15;
#pragma unroll
        for (int ks = 0; ks < 8; ++ks) {
          const int j = ks * 4 + quad;
          const bf16x8 kf = *(const bf16x8*)&ksb[row * 256 + ((j ^ (row & 31)) << 3)];
          acc = mfma16(qf[ks], kf, acc);
        }
        sf[nt] = acc;
      }

      const bool lastTile = (kt == ntiles - 1);
      float mx[4];
#pragma unroll
      for (int r = 0; r < 4; ++r) {
        const int qg = q0 + quad * 4 + r;
        float v = -3e38f;
#pragma unroll
        for (int nt = 0; nt < 4; ++nt) {
          float s = sf[nt][r] * SCL;
          if (lastTile) {
            const int kg = kt * 64 + nt * 16 + l15;
            if (kg > qg) s = -3e38f;
          }
          sf[nt][r] = s;
          v = fmaxf(v, s);
        }
        mx[r] = rmax16(v);
      }

      float g = 0.f;
#pragma unroll
      for (int r = 0; r < 4; ++r) g = fmaxf(g, mx[r] - mrun[r]);
      const bool resc = !__all(g <= 8.0f);
      f32x4 av;
      if (resc) {
#pragma unroll
        for (int r = 0; r < 4; ++r) {
          const float mn = fmaxf(mrun[r], mx[r]);
          av[r] = __expf(mrun[r] - mn);
          mrun[r] = mn;
          lrun[r] *= av[r];
        }
      }

#pragma unroll
      for (int r = 0; r < 4; ++r) {
        float sum = 0.f;
#pragma unroll
        for (int nt = 0; nt < 4; ++nt) {
          const float pv = __expf(sf[nt][r] - mrun[r]);
          Pl[w][quad * 4 + r][nt * 16 + l15] = (bf16_t)pv;
          sum += pv;
        }
        lrun[r] += rsum16(sum);
      }
      if (resc) {
#pragma unroll
        for (int dt = 0; dt < 16; ++dt) of[dt] *= av;
      }
      __asm__ volatile("s_waitcnt lgkmcnt(0)" ::: "memory");

      bf16x8 pa[2];
#pragma unroll
      for (int k2 = 0; k2 < 2; ++k2)
        pa[k2] = *(const bf16x8*)&Pl[w][l15][k2 * 32 + quad * 8];
#pragma unroll
      for (int dt = 0; dt < 16; ++dt) {
        const int row = dt * 16 + l15;
#pragma unroll
        for (int k2 = 0; k2 < 2; ++k2) {
          const int j = k2 * 4 + quad;
          const bf16x8 vf = *(const bf16x8*)&vsb[row * 64 + ((j ^ (row & 7)) << 3)];
          of[dt] = mfma16(pa[k2], vf, of[dt]);
        }
      }

      __syncthreads();
      cur ^= 1;
    }

    f32x4 iv;
#pragma unroll
    for (int r = 0; r < 4; ++r) iv[r] = 1.0f / lrun[r];
#pragma unroll
    for (int dt = 0; dt < 16; ++dt) {
      const f32x4 o = of[dt] * iv;
#pragma unroll
      for (int r = 0; r < 4; ++r)
        O[(size_t)(b * SEQ + q0 + quad * 4 + r) * HID + (size_t)h * HD + dt * 16 + l15] =
            (bf16_t)o[r];
    }
  }
}

// ---------- launch ----------
extern "C" void kernel_launch(void* const* d_in, const int* in_sizes, int n_in,
                              void* d_out, int out_size, void* d_ws, size_t ws_size,
                              hipStream_t stream) {
  const float* hidden  = (const float*)d_in[0];
  const int* positions = (const int*)d_in[1];
  const float* w_qkv   = (const float*)d_in[2];
  const float* w_o     = (const float*)d_in[3];
  float* out           = (float*)d_out;

  char* ws = (char*)d_ws;
  bf16_t* hiddenB = (bf16_t*)ws; ws += (size_t)8192 * 2048 * 2;   // 33.5 MB
  bf16_t* wqkvT   = (bf16_t*)ws; ws += (size_t)2560 * 2048 * 2;   // 10.5 MB
  bf16_t* woT     = (bf16_t*)ws; ws += (size_t)2048 * 2048 * 2;   //  8.4 MB
  bf16_t* qkvB    = (bf16_t*)ws; ws += (size_t)8192 * 2560 * 2;   // 41.9 MB
  bf16_t* VtB     = (bf16_t*)ws; ws += (size_t)4 * 256 * 2048 * 2;//  4.2 MB
  bf16_t* attnB   = (bf16_t*)ws;                                  // 33.5 MB

  // rope table aliases the attnB region (2 MB << 33.5 MB); consumed before
  // attn_kernel writes attnB.
  float2* ropeTab = (float2*)attnB;

  cvt_bf16_kernel<<<8192, 256, 0, stream>>>(hidden, hiddenB);
  transw_kernel<<<dim3(QKVN / 64, HID / 64), 256, 0, stream>>>(w_qkv, wqkvT, HID, QKVN);
  transw_kernel<<<dim3(HID / 64, HID / 64), 256, 0, stream>>>(w_o, woT, HID, HID);
  rope_table_kernel<<<SEQ, 128, 0, stream>>>(positions, ropeTab);

  gemm256_kernel<bf16_t><<<dim3(QKVN / 256, 8192 / 256), 512, 0, stream>>>
      (hiddenB, wqkvT, qkvB, 8192, QKVN, HID);

  rope_kernel<<<dim3(BATCH * SEQ / 16, 9), 256, 0, stream>>>(ropeTab, qkvB);
  vtrans_kernel<<<dim3(SEQ / 64, HD / 64, BATCH), 256, 0, stream>>>(qkvB, VtB);

  attn_kernel<<<256, 512, 0, stream>>>(qkvB, VtB, attnB);

  gemm256_kernel<float><<<dim3(HID / 256, 8192 / 256), 512, 0, stream>>>
      (attnB, woT, out, 8192, HID, HID);
}

// Round 12
// 455.649 us; speedup vs baseline: 1.0863x; 1.0863x over previous
//
#include <hip/hip_runtime.h>
#include <math.h>

constexpr int BATCH = 4;
constexpr int SEQ   = 2048;
constexpr int HID   = 2048;
constexpr int NHEAD = 8;
constexpr int HD    = 256;
constexpr int QKVN  = (NHEAD + 2) * HD;          // 2560
constexpr float SCL = 0.0625f;                   // 256^-0.5

typedef __bf16 bf16_t;
typedef __bf16 bf16x8 __attribute__((ext_vector_type(8)));
typedef float  f32x4  __attribute__((ext_vector_type(4)));

__device__ __forceinline__ f32x4 zero4() {
  f32x4 z; z[0] = 0.f; z[1] = 0.f; z[2] = 0.f; z[3] = 0.f; return z;
}

__device__ __forceinline__ f32x4 mfma16(bf16x8 a, bf16x8 b, f32x4 c) {
  return __builtin_amdgcn_mfma_f32_16x16x32_bf16(a, b, c, 0, 0, 0);
}

// async global->LDS, 16B per lane. lds must be wave-uniform base; HW adds lane*16.
__device__ __forceinline__ void gl2lds16(const void* g, void* lds) {
  typedef __attribute__((address_space(1))) void* gp_t;
  typedef __attribute__((address_space(3))) void* lp_t;
  __builtin_amdgcn_global_load_lds((gp_t)(size_t)g,
                                   (lp_t)(unsigned int)(size_t)lds, 16, 0, 0);
}

__device__ __forceinline__ float rmax16(float v) {
#pragma unroll
  for (int o = 1; o < 16; o <<= 1) v = fmaxf(v, __shfl_xor(v, o));
  return v;
}
__device__ __forceinline__ float rsum16(float v) {
#pragma unroll
  for (int o = 1; o < 16; o <<= 1) v += __shfl_xor(v, o);
  return v;
}

// ---------- fp32 -> bf16 bulk convert (8 elems/thread) ----------
__global__ __launch_bounds__(256)
void cvt_bf16_kernel(const float* __restrict__ in, bf16_t* __restrict__ out) {
  const int i = blockIdx.x * 256 + threadIdx.x;
  const float4 a = ((const float4*)in)[i * 2];
  const float4 b = ((const float4*)in)[i * 2 + 1];
  bf16x8 o;
  o[0] = (bf16_t)a.x; o[1] = (bf16_t)a.y; o[2] = (bf16_t)a.z; o[3] = (bf16_t)a.w;
  o[4] = (bf16_t)b.x; o[5] = (bf16_t)b.y; o[6] = (bf16_t)b.z; o[7] = (bf16_t)b.w;
  ((bf16x8*)out)[i] = o;
}

// ---------- w[K][N] fp32 -> wT[N][K] bf16, 64x64 tiles ----------
__global__ __launch_bounds__(256)
void transw_kernel(const float* __restrict__ w, bf16_t* __restrict__ wT, int K, int N) {
  __shared__ __align__(16) bf16_t tile[64][72];
  const int n0 = blockIdx.x * 64, k0 = blockIdx.y * 64;
  const int t = threadIdx.x, rr = t >> 3, c8 = (t & 7) * 8;
#pragma unroll
  for (int it = 0; it < 2; ++it) {
    const int r = rr + it * 32;
    const float4* p = (const float4*)(w + (size_t)(k0 + r) * N + n0 + c8);
    const float4 a = p[0], b = p[1];
    bf16x8 o;
    o[0] = (bf16_t)a.x; o[1] = (bf16_t)a.y; o[2] = (bf16_t)a.z; o[3] = (bf16_t)a.w;
    o[4] = (bf16_t)b.x; o[5] = (bf16_t)b.y; o[6] = (bf16_t)b.z; o[7] = (bf16_t)b.w;
    *(bf16x8*)&tile[r][c8] = o;
  }
  __syncthreads();
#pragma unroll
  for (int it = 0; it < 2; ++it) {
    const int rn = rr + it * 32;
    bf16x8 o;
#pragma unroll
    for (int j = 0; j < 8; ++j) o[j] = tile[c8 + j][rn];
    *(bf16x8*)&wT[(size_t)(n0 + rn) * K + k0 + c8] = o;
  }
}

// =====================================================================
// 256x256 8-phase GEMM (m201 template, plain HIP): C[M][N] = A * BT^T
// + T1 bijective XCD swizzle.
// ROUND-12 FIX: LGKM0 no longer contains sched_barrier(0). Rule #18's
// sched_barrier is only needed for inline-asm ds_reads; ours are compiler
// ds_reads (compiler emits its own fine-grained lgkmcnt). Pinning the
// schedule at 8 points/iter is m141's exact regression (510 TF) -- matching
// our measured ~500-580 TF. Barrier/waitcnt PLACEMENT unchanged from the
// R10 code that passed absmax.
// =====================================================================
#define BAR()   __builtin_amdgcn_s_barrier()
#define LGKM0() asm volatile("s_waitcnt lgkmcnt(0)" ::: "memory")
#define VMC(n)  asm volatile("s_waitcnt vmcnt(" #n ")" ::: "memory")

template <typename TC>
__global__ __launch_bounds__(512)
void gemm256_kernel(const bf16_t* __restrict__ A, const bf16_t* __restrict__ BT,
                    TC* __restrict__ C, int M, int N, int K) {
  __shared__ __align__(16) bf16_t As[2][2][128 * 64];   // [buf][half] 64 KB
  __shared__ __align__(16) bf16_t Bs[2][2][128 * 64];   // 64 KB

  const int tid = threadIdx.x;
  const int w = tid >> 6, lane = tid & 63;
  const int wr = w >> 2, wc = w & 3;
  const int quad = lane >> 4, l15 = lane & 15;

  // T1: XCD-aware bijective remap (nwg % 8 == 0 for both launches)
  const int gx = gridDim.x;
  const int nwg = gx * gridDim.y;
  const int flat = blockIdx.y * gx + blockIdx.x;
  const int cpx = nwg >> 3;
  const int swz = (flat & 7) * cpx + (flat >> 3);
  const int bm = (swz / gx) * 256, bn = (swz % gx) * 256;

  const int srow = tid >> 3;                    // 0..63 row within 64-row chunk
  const int sc16 = (tid & 7) ^ (srow & 7);      // pre-swizzled source chunk
  const bf16_t* Asrc = A  + (size_t)(bm + srow) * K + sc16 * 8;
  const bf16_t* Bsrc = BT + (size_t)(bn + srow) * K + sc16 * 8;

#define STAGE_A(t, h) do {                                                  \
    const bf16_t* _s = Asrc + (size_t)((h) * 128) * K + (t) * 64;           \
    gl2lds16(_s,                 &As[(t) & 1][h][w * 512]);                 \
    gl2lds16(_s + (size_t)64 * K, &As[(t) & 1][h][4096 + w * 512]);         \
  } while (0)
#define STAGE_B(t, h) do {                                                  \
    const bf16_t* _s = Bsrc + (size_t)((h) * 128) * K + (t) * 64;           \
    gl2lds16(_s,                 &Bs[(t) & 1][h][w * 512]);                 \
    gl2lds16(_s + (size_t)64 * K, &Bs[(t) & 1][h][4096 + w * 512]);         \
  } while (0)

  const int c0  = ((quad ^ (l15 & 7)) << 3);
  const int aro = l15 * 64;                     // + mt*1024
  const int bh  = wc >> 1;
  const int bro = ((wc & 1) * 64 + l15) * 64;   // + nt*1024

  f32x4 acc[8][4];
#pragma unroll
  for (int mt = 0; mt < 8; ++mt)
#pragma unroll
    for (int nt = 0; nt < 4; ++nt) acc[mt][nt] = zero4();

  bf16x8 bfr[4][2], a01[2][2], a2[6][2];

#define LD_B(b) do { _Pragma("unroll")                                      \
    for (int nt = 0; nt < 4; ++nt) {                                        \
      bfr[nt][0] = *(const bf16x8*)&Bs[b][bh][bro + nt * 1024 + c0];        \
      bfr[nt][1] = *(const bf16x8*)&Bs[b][bh][bro + nt * 1024 + (c0 ^ 32)]; \
    } } while (0)
#define LD_A01(b) do { _Pragma("unroll")                                    \
    for (int mt = 0; mt < 2; ++mt) {                                        \
      a01[mt][0] = *(const bf16x8*)&As[b][wr][aro + mt * 1024 + c0];        \
      a01[mt][1] = *(const bf16x8*)&As[b][wr][aro + mt * 1024 + (c0 ^ 32)]; \
    } } while (0)
#define LD_A2(b) do { _Pragma("unroll")                                     \
    for (int i = 0; i < 6; ++i) {                                           \
      a2[i][0] = *(const bf16x8*)&As[b][wr][aro + (i + 2) * 1024 + c0];     \
      a2[i][1] = *(const bf16x8*)&As[b][wr][aro + (i + 2) * 1024 + (c0^32)];\
    } } while (0)
#define MFMA8(A0, A1, mb) do {                                              \
    __builtin_amdgcn_s_setprio(1);                                          \
    _Pragma("unroll")                                                       \
    for (int nt = 0; nt < 4; ++nt) {                                        \
      acc[(mb)][nt]     = mfma16((A0)[0], bfr[nt][0], acc[(mb)][nt]);       \
      acc[(mb)][nt]     = mfma16((A0)[1], bfr[nt][1], acc[(mb)][nt]);       \
      acc[(mb)+1][nt]   = mfma16((A1)[0], bfr[nt][0], acc[(mb)+1][nt]);     \
      acc[(mb)+1][nt]   = mfma16((A1)[1], bfr[nt][1], acc[(mb)+1][nt]);     \
    }                                                                       \
    __builtin_amdgcn_s_setprio(0);                                          \
  } while (0)

  const int NITER = K >> 7;                     // K/128 (two BK=64 tiles/iter)

  STAGE_A(0, 0); STAGE_A(0, 1); STAGE_B(0, 0); STAGE_B(0, 1);
  STAGE_A(1, 0); STAGE_A(1, 1);
  VMC(4);
  BAR();

  for (int u = 0; u < NITER; ++u) {
    const bool last = (u == NITER - 1);
    const int t1 = 2 * u + 1, t2 = 2 * u + 2, t3 = 2 * u + 3;

    LD_B(0); LD_A01(0);
    STAGE_B(t1, 0);
    BAR(); LGKM0();
    MFMA8(a01[0], a01[1], 0);
    BAR();
    LD_A2(0);
    STAGE_B(t1, 1);
    BAR(); LGKM0();
    MFMA8(a2[0], a2[1], 2);
    BAR();
    if (!last) STAGE_A(t2, 0);
    BAR();
    MFMA8(a2[2], a2[3], 4);
    BAR();
    if (!last) { STAGE_A(t2, 1); VMC(4); } else { VMC(0); }
    BAR();
    MFMA8(a2[4], a2[5], 6);
    BAR();
    LD_B(1); LD_A01(1);
    if (!last) STAGE_B(t2, 0);
    BAR(); LGKM0();
    MFMA8(a01[0], a01[1], 0);
    BAR();
    LD_A2(1);
    if (!last) STAGE_B(t2, 1);
    BAR(); LGKM0();
    MFMA8(a2[0], a2[1], 2);
    BAR();
    if (!last) STAGE_A(t3, 0);
    BAR();
    MFMA8(a2[2], a2[3], 4);
    BAR();
    if (!last) { STAGE_A(t3, 1); VMC(4); }
    BAR();
    MFMA8(a2[4], a2[5], 6);
    BAR();
  }

#pragma unroll
  for (int mt = 0; mt < 8; ++mt)
#pragma unroll
    for (int nt = 0; nt < 4; ++nt)
#pragma unroll
      for (int r = 0; r < 4; ++r) {
        const int row = bm + wr * 128 + mt * 16 + quad * 4 + r;
        const int col = bn + wc * 64 + nt * 16 + l15;
        C[(size_t)row * N + col] = (TC)acc[mt][nt][r];
      }
#undef STAGE_A
#undef STAGE_B
#undef LD_B
#undef LD_A01
#undef LD_A2
#undef MFMA8
}

// ---------- RoPE cos/sin table: tab[s][i] = (cos, sin) ----------
__global__ __launch_bounds__(128)
void rope_table_kernel(const int* __restrict__ pos, float2* __restrict__ tab) {
  const int s = blockIdx.x, i = threadIdx.x;
  const float inv_freq = powf(10000.0f, -(float)i / 128.0f);
  const float ang = (float)pos[s] * inv_freq;
  float sn, cs;
  sincosf(ang, &sn, &cs);
  tab[s * 128 + i] = make_float2(cs, sn);
}

// ---------- RoPE apply, table-driven, bf16x8 vectorized ----------
__global__ __launch_bounds__(256)
void rope_kernel(const float2* __restrict__ tab, bf16_t* __restrict__ qkv) {
  const int bs = blockIdx.x * 16 + (threadIdx.x >> 4);
  const int h  = blockIdx.y;
  const int i0 = (threadIdx.x & 15) * 8;
  const int s  = bs & (SEQ - 1);
  const size_t base = (size_t)bs * QKVN + (size_t)h * HD;
  bf16x8 a = *(const bf16x8*)&qkv[base + i0];
  bf16x8 b = *(const bf16x8*)&qkv[base + 128 + i0];
  bf16x8 oa, ob;
#pragma unroll
  for (int j = 0; j < 8; ++j) {
    const float2 t = tab[s * 128 + i0 + j];
    const float x1 = (float)a[j], x2 = (float)b[j];
    oa[j] = (bf16_t)(x1 * t.x - x2 * t.y);
    ob[j] = (bf16_t)(x2 * t.x + x1 * t.y);
  }
  *(bf16x8*)&qkv[base + i0]       = oa;
  *(bf16x8*)&qkv[base + 128 + i0] = ob;
}

// ---------- V transpose: qkv v-part [s][d] -> Vt[b][d][s] ----------
__global__ __launch_bounds__(256)
void vtrans_kernel(const bf16_t* __restrict__ qkv, bf16_t* __restrict__ Vt) {
  __shared__ __align__(16) bf16_t tile[64][72];
  const int s0 = blockIdx.x * 64, d0 = blockIdx.y * 64, b = blockIdx.z;
  const int t = threadIdx.x, rr = t >> 3, c8 = (t & 7) * 8;
#pragma unroll
  for (int it = 0; it < 2; ++it) {
    const int r = rr + it * 32;
    *(bf16x8*)&tile[r][c8] =
        *(const bf16x8*)&qkv[(size_t)(b * SEQ + s0 + r) * QKVN + 2304 + d0 + c8];
  }
  __syncthreads();
#pragma unroll
  for (int it = 0; it < 2; ++it) {
    const int dd = rr + it * 32;
    bf16x8 o;
#pragma unroll
    for (int j = 0; j < 8; ++j) o[j] = tile[c8 + j][dd];
    *(bf16x8*)&Vt[(size_t)(b * HD + d0 + dd) * SEQ + s0 + c8] = o;
  }
}

// ---------- flash attention (round-1 config: PROVEN LOCAL OPTIMUM, 137.6 us)
// 8 waves = 8 heads share K/V tiles; fused complementary q-pair (qt, 127-qt)
// per block -> uniform ~33 K-tile iterations; 2-phase prefetch (stage kt+1
// into buf^1 while computing kt). 9 structural variants all regressed.
__global__ __launch_bounds__(512)
void attn_kernel(const bf16_t* __restrict__ qkv, const bf16_t* __restrict__ Vt,
                 bf16_t* __restrict__ O) {
  __shared__ __align__(16) bf16_t Ks[2][64 * 256];
  __shared__ __align__(16) bf16_t Vts[2][256 * 64];
  __shared__ __align__(16) bf16_t Pl[8][16][72];

  const int tid = threadIdx.x, w = tid >> 6, lane = tid & 63;
  const int quad = lane >> 4, l15 = lane & 15;
  const int b = blockIdx.x >> 6;
  const int qtR = blockIdx.x & 63;
  const int h = w;

  const int krow_base = w * 2 + (lane >> 5);
  const int kcol = lane & 31;
  const int vrow_base = w * 8 + (lane >> 3);
  const int vcol = lane & 7;

  const bf16_t* kbase0 = qkv + (size_t)(b * SEQ) * QKVN + 2048;
  const bf16_t* vbase0 = Vt + (size_t)b * HD * SEQ;

  auto stage = [&](int kt, int buf) {
    const bf16_t* kbase = kbase0 + (size_t)(kt * 64) * QKVN;
#pragma unroll
    for (int i = 0; i < 4; ++i) {
      const int r = i * 16 + krow_base;
      gl2lds16(kbase + (size_t)r * QKVN + ((kcol ^ (r & 31)) << 3),
               &Ks[buf][(i * 512 + w * 64) * 8]);
    }
    const bf16_t* vbase = vbase0 + kt * 64;
#pragma unroll
    for (int i = 0; i < 4; ++i) {
      const int r = i * 64 + vrow_base;
      gl2lds16(vbase + (size_t)r * SEQ + ((vcol ^ (r & 7)) << 3),
               &Vts[buf][(i * 512 + w * 64) * 8]);
    }
  };

  for (int phase = 0; phase < 2; ++phase) {
    const int qt = phase ? (127 - qtR) : qtR;
    const int q0 = qt * 16;

    bf16x8 qf[8];
    const bf16_t* qp =
        qkv + (size_t)(b * SEQ + q0 + l15) * QKVN + (size_t)h * HD + quad * 8;
#pragma unroll
    for (int ks = 0; ks < 8; ++ks) qf[ks] = *(const bf16x8*)(qp + ks * 32);

    float mrun[4], lrun[4];
    f32x4 of[16];
#pragma unroll
    for (int r = 0; r < 4; ++r) { mrun[r] = -3e38f; lrun[r] = 0.f; }
#pragma unroll
    for (int dt = 0; dt < 16; ++dt) of[dt] = zero4();

    const int ntiles = q0 / 64 + 1;
    int cur = 0;
    stage(0, 0);
    __syncthreads();

    for (int kt = 0; kt < ntiles; ++kt) {
      if (kt + 1 < ntiles) stage(kt + 1, cur ^ 1);

      const bf16_t* ksb = Ks[cur];
      const bf16_t* vsb = Vts[cur];

      f32x4 sf[4];
#pragma unroll
      for (int nt = 0; nt < 4; ++nt) {
        f32x4 acc = zero4();
        const int row = nt * 16 + l15;
#pragma unroll
        for (int ks = 0; ks < 8; ++ks) {
          const int j = ks * 4 + quad;
          const bf16x8 kf = *(const bf16x8*)&ksb[row * 256 + ((j ^ (row & 31)) << 3)];
          acc = mfma16(qf[ks], kf, acc);
        }
        sf[nt] = acc;
      }

      const bool lastTile = (kt == ntiles - 1);
      float mx[4];
#pragma unroll
      for (int r = 0; r < 4; ++r) {
        const int qg = q0 + quad * 4 + r;
        float v = -3e38f;
#pragma unroll
        for (int nt = 0; nt < 4; ++nt) {
          float s = sf[nt][r] * SCL;
          if (lastTile) {
            const int kg = kt * 64 + nt * 16 + l15;
            if (kg > qg) s = -3e38f;
          }
          sf[nt][r] = s;
          v = fmaxf(v, s);
        }
        mx[r] = rmax16(v);
      }

      float g = 0.f;
#pragma unroll
      for (int r = 0; r < 4; ++r) g = fmaxf(g, mx[r] - mrun[r]);
      const bool resc = !__all(g <= 8.0f);
      f32x4 av;
      if (resc) {
#pragma unroll
        for (int r = 0; r < 4; ++r) {
          const float mn = fmaxf(mrun[r], mx[r]);
          av[r] = __expf(mrun[r] - mn);
          mrun[r] = mn;
          lrun[r] *= av[r];
        }
      }

#pragma unroll
      for (int r = 0; r < 4; ++r) {
        float sum = 0.f;
#pragma unroll
        for (int nt = 0; nt < 4; ++nt) {
          const float pv = __expf(sf[nt][r] - mrun[r]);
          Pl[w][quad * 4 + r][nt * 16 + l15] = (bf16_t)pv;
          sum += pv;
        }
        lrun[r] += rsum16(sum);
      }
      if (resc) {
#pragma unroll
        for (int dt = 0; dt < 16; ++dt) of[dt] *= av;
      }
      __asm__ volatile("s_waitcnt lgkmcnt(0)" ::: "memory");

      bf16x8 pa[2];
#pragma unroll
      for (int k2 = 0; k2 < 2; ++k2)
        pa[k2] = *(const bf16x8*)&Pl[w][l15][k2 * 32 + quad * 8];
#pragma unroll
      for (int dt = 0; dt < 16; ++dt) {
        const int row = dt * 16 + l15;
#pragma unroll
        for (int k2 = 0; k2 < 2; ++k2) {
          const int j = k2 * 4 + quad;
          const bf16x8 vf = *(const bf16x8*)&vsb[row * 64 + ((j ^ (row & 7)) << 3)];
          of[dt] = mfma16(pa[k2], vf, of[dt]);
        }
      }

      __syncthreads();
      cur ^= 1;
    }

    f32x4 iv;
#pragma unroll
    for (int r = 0; r < 4; ++r) iv[r] = 1.0f / lrun[r];
#pragma unroll
    for (int dt = 0; dt < 16; ++dt) {
      const f32x4 o = of[dt] * iv;
#pragma unroll
      for (int r = 0; r < 4; ++r)
        O[(size_t)(b * SEQ + q0 + quad * 4 + r) * HID + (size_t)h * HD + dt * 16 + l15] =
            (bf16_t)o[r];
    }
  }
}

// ---------- launch ----------
extern "C" void kernel_launch(void* const* d_in, const int* in_sizes, int n_in,
                              void* d_out, int out_size, void* d_ws, size_t ws_size,
                              hipStream_t stream) {
  const float* hidden  = (const float*)d_in[0];
  const int* positions = (const int*)d_in[1];
  const float* w_qkv   = (const float*)d_in[2];
  const float* w_o     = (const float*)d_in[3];
  float* out           = (float*)d_out;

  char* ws = (char*)d_ws;
  bf16_t* hiddenB = (bf16_t*)ws; ws += (size_t)8192 * 2048 * 2;   // 33.5 MB
  bf16_t* wqkvT   = (bf16_t*)ws; ws += (size_t)2560 * 2048 * 2;   // 10.5 MB
  bf16_t* woT     = (bf16_t*)ws; ws += (size_t)2048 * 2048 * 2;   //  8.4 MB
  bf16_t* qkvB    = (bf16_t*)ws; ws += (size_t)8192 * 2560 * 2;   // 41.9 MB
  bf16_t* VtB     = (bf16_t*)ws; ws += (size_t)4 * 256 * 2048 * 2;//  4.2 MB
  bf16_t* attnB   = (bf16_t*)ws;                                  // 33.5 MB

  // rope table aliases the attnB region (2 MB << 33.5 MB); consumed before
  // attn_kernel writes attnB.
  float2* ropeTab = (float2*)attnB;

  cvt_bf16_kernel<<<8192, 256, 0, stream>>>(hidden, hiddenB);
  transw_kernel<<<dim3(QKVN / 64, HID / 64), 256, 0, stream>>>(w_qkv, wqkvT, HID, QKVN);
  transw_kernel<<<dim3(HID / 64, HID / 64), 256, 0, stream>>>(w_o, woT, HID, HID);
  rope_table_kernel<<<SEQ, 128, 0, stream>>>(positions, ropeTab);

  gemm256_kernel<bf16_t><<<dim3(QKVN / 256, 8192 / 256), 512, 0, stream>>>
      (hiddenB, wqkvT, qkvB, 8192, QKVN, HID);

  rope_kernel<<<dim3(BATCH * SEQ / 16, 9), 256, 0, stream>>>(ropeTab, qkvB);
  vtrans_kernel<<<dim3(SEQ / 64, HD / 64, BATCH), 256, 0, stream>>>(qkvB, VtB);

  attn_kernel<<<256, 512, 0, stream>>>(qkvB, VtB, attnB);

  gemm256_kernel<float><<<dim3(HID / 256, 8192 / 256), 512, 0, stream>>>
      (attnB, woT, out, 8192, HID, HID);
}